// Round 13
// baseline (218.843 us; speedup 1.0000x reference)
//
#include <hip/hip_runtime.h>
#include <math.h>

// Problem constants: bs=32, en=256, dx=512, dz=256, heads=8, dh=32, L=1280.
//
// Mask is block-diagonal eyes: q<256 -> one-hot row; q=256+j -> exactly 4
// nonzeros {q, 512+j, 768+j, 1024+j}. Wk folded into the query side; pe-dot
// and bk-dot are constant across the 4 softmax candidates -> cancel.
// Needed per (b,j,h):  dR_m = sum_e raw_m*w,  dO = sum_e w,
// with w = wu[j,h,e] + wv[b,h,e].
//
// Pipeline (3 launches):
//   L1 k_uv_copy : u,v projections (288 blks) || out0 state-copy (1024 blks)
//   L2 k_w_onehot: wu2,wv (512 blks)          || out1 one-hot rows (1024 blks)
//   L3 k_dotfin  : R11 data-LDS dot (1024 blks, 2/CU occupancy) + FAN-IN:
//                  per (jt,b) pair the last-arriving eq-block finalizes
//                  (reduce 2 records -> softmax -> dependent output writes),
//                  overlapping output stores with remaining dot compute.
//
// ws layout (floats): u[256][256]@0, v[32][256]@65536, wu2[8][256e][256j]@73728,
// wv[32][8][256e]@598016, pws@663552 (720896), cnt@1384448 (512 ints).

// ---------------------------------------------------------------- k_uv_copy
__global__ __launch_bounds__(256)
void k_uv_copy(const float* __restrict__ Q, const float* __restrict__ Wq,
               const float* __restrict__ bq, const float* __restrict__ state,
               float* __restrict__ u, float* __restrict__ v,
               float* __restrict__ out0) {
  const int blk = blockIdx.x;
  const int t = threadIdx.x;
  if (blk < 288) {
    __shared__ float row[256];
    float rv;
    if (blk < 256) {
      rv = Q[(256 + blk) * 256 + t];
    } else {
      const int b = blk - 256;
      // sinusoidal PE over the BATCH axis (faithful quirk): pos=b, d_model=256
      const float dv = expf(-9.210340371976184f * (float)((t >> 1) << 1) * (1.0f / 256.0f));
      const float ang = (float)b * dv;
      rv = (t & 1) ? cosf(ang) : sinf(ang);
    }
    row[t] = rv;
    __syncthreads();
    float acc = (blk < 256) ? 0.0f : bq[t];
    for (int e = 0; e < 256; ++e) acc += row[e] * Wq[e * 256 + t];
    if (blk < 256) u[blk * 256 + t] = acc;
    else           v[(blk - 256) * 256 + t] = acc;
  } else {
    // role B: copy q<256 half of out0 (8 e-rows x 256 cols per block)
    const int id = blk - 288;      // 0..1023
    const int b = id >> 5, eg = id & 31;
    const int r = t >> 5;          // 0..7
    const int c = t & 31;          // 0..31 (float4 col)
    const int e = eg * 8 + r;
    const size_t base = ((size_t)(b * 256 + e)) * 512;
    *(float4*)(out0 + base + c * 4)        = *(const float4*)(state + base + c * 4);
    *(float4*)(out0 + base + (c + 32) * 4) = *(const float4*)(state + base + (c + 32) * 4);
  }
}

// ---------------------------------------------------------------- k_w_onehot
__global__ __launch_bounds__(256)
void k_w_onehot(const float* __restrict__ Wk, const float* __restrict__ u,
                const float* __restrict__ v, float* __restrict__ wu2,
                float* __restrict__ wv, float* __restrict__ out1) {
  const int blk = blockIdx.x;
  const int t = threadIdx.x;
  if (blk < 512) {
    const int e = blk & 255;
    const int part = blk >> 8;     // 0 -> wu2, 1 -> wv
    __shared__ float wrow[256];
    wrow[t] = Wk[e * 256 + t];
    __syncthreads();
    if (part == 0) {
      const float* ur = u + t * 256;
#pragma unroll
      for (int h = 0; h < 8; ++h) {
        float acc = 0.0f;
#pragma unroll
        for (int d = 0; d < 32; ++d) acc += ur[h * 32 + d] * wrow[h * 32 + d];
        wu2[(h * 256 + e) * 256 + t] = acc;
      }
    } else if (t < 32) {
      const float* vr = v + t * 256;
#pragma unroll
      for (int h = 0; h < 8; ++h) {
        float acc = 0.0f;
#pragma unroll
        for (int d = 0; d < 32; ++d) acc += vr[h * 32 + d] * wrow[h * 32 + d];
        wv[(t * 8 + h) * 256 + e] = acc;
      }
    }
  } else {
    // role C: out1 one-hot rows q<256 (8 rows per block, 320 float4 per row)
    const int id = blk - 512;      // 0..1023
    const int b = id >> 5, qg = id & 31;
#pragma unroll
    for (int k = 0; k < 8; ++k) {
      const int q = qg * 8 + k;
      float4* row = (float4*)(out1 + ((size_t)(b * 512 + q)) * 1280);
      float4 o = make_float4(0.f, 0.f, 0.f, 0.f);
      if (t == (q >> 2)) {
        const int comp = q & 3;
        if (comp == 0) o.x = 1.f; else if (comp == 1) o.y = 1.f;
        else if (comp == 2) o.z = 1.f; else o.w = 1.f;
      }
      row[t] = o;
      if (t < 64) row[256 + t] = make_float4(0.f, 0.f, 0.f, 0.f);
    }
  }
}

// ---------------------------------------------------------------- k_dotfin
// grid (16 jt, 2 eq, 32 b), 512 threads = 8 waves. R11 k_dot internals
// (data tile in LDS pad-17, wu2 global/L2, ~51.6 KB LDS -> 2 blocks/CU),
// then fan-in: last-arriving eq-block of each (jt,b) pair finalizes.
__global__ __launch_bounds__(512)
void k_dotfin(const float* __restrict__ state, const float* __restrict__ o0,
              const float* __restrict__ o1, const float* __restrict__ o2,
              const float* __restrict__ wu2, const float* __restrict__ wv,
              float* __restrict__ pws, int* __restrict__ cnt,
              float* __restrict__ out0, float* __restrict__ out1) {
  const int t = threadIdx.x;
  const int jt = blockIdx.x;       // 0..15
  const int eq = blockIdx.y;       // 0..1
  const int b  = blockIdx.z;       // 0..31

  __shared__ float s_data[4][128][17];  // 34.8 KB
  __shared__ float s_wv[1024];          //  4.0 KB
  __shared__ float s_part[8][16][25];   // 12.8 KB
  __shared__ float s_a[16][4];
  __shared__ int s_go;

  // ---- stage data tile: cell = (e = t>>2, jq = t&3), all 4 m-arrays
  {
    const int e = t >> 2;          // 0..127
    const int jq = t & 3;          // 0..3
    const int ge = eq * 128 + e;   // global e
    const int j0 = jt * 16 + jq * 4;
    const float4 vs = *(const float4*)(state + ((size_t)(b * 256 + ge)) * 512 + 256 + j0);
    const float4 v0 = *(const float4*)(o0 + ((size_t)(b * 256 + ge)) * 256 + j0);
    const float4 v1 = *(const float4*)(o1 + ((size_t)(b * 256 + ge)) * 256 + j0);
    const float4 v2 = *(const float4*)(o2 + ((size_t)(b * 256 + ge)) * 256 + j0);
    const int jb = jq * 4;
    s_data[0][e][jb] = vs.x; s_data[0][e][jb+1] = vs.y; s_data[0][e][jb+2] = vs.z; s_data[0][e][jb+3] = vs.w;
    s_data[1][e][jb] = v0.x; s_data[1][e][jb+1] = v0.y; s_data[1][e][jb+2] = v0.z; s_data[1][e][jb+3] = v0.w;
    s_data[2][e][jb] = v1.x; s_data[2][e][jb+1] = v1.y; s_data[2][e][jb+2] = v1.z; s_data[2][e][jb+3] = v1.w;
    s_data[3][e][jb] = v2.x; s_data[3][e][jb+1] = v2.y; s_data[3][e][jb+2] = v2.z; s_data[3][e][jb+3] = v2.w;
  }
  for (int i = t; i < 1024; i += 512)
    s_wv[i] = wv[b * 2048 + (i >> 7) * 256 + eq * 128 + (i & 127)];
  __syncthreads();

  const int jl = t & 15;
  const int es = (t >> 4) & 15;    // 0..15
  const int hp = t >> 8;           // 0..1
  const int j = jt * 16 + jl;

  // acc[hh*5+c]: c=0..3 dR(state,o0,o1,o2), c=4 dO(ones); 20..23 raw sums
  float acc[24];
#pragma unroll
  for (int k = 0; k < 24; ++k) acc[k] = 0.f;

  const float* pwu = wu2 + (size_t)hp * 4 * 256 * 256 + j;  // + (hh*256+e)*256
  const float* pwv = s_wv + hp * 4 * 128;                   // + hh*128+el

#pragma unroll
  for (int it = 0; it < 8; ++it) {
    const int el = es * 8 + it;    // 0..127 within this eq slice
    const int e = eq * 128 + el;   // global e
    const float s  = s_data[0][el][jl];
    const float x0 = s_data[1][el][jl];
    const float x1 = s_data[2][el][jl];
    const float x2 = s_data[3][el][jl];
    acc[20] += s; acc[21] += x0; acc[22] += x1; acc[23] += x2;
#pragma unroll
    for (int hh = 0; hh < 4; ++hh) {
      const float w = pwu[(size_t)(hh * 256 + e) * 256] + pwv[hh * 128 + el];
      acc[hh * 5 + 0] += s * w;  acc[hh * 5 + 1] += x0 * w;
      acc[hh * 5 + 2] += x1 * w; acc[hh * 5 + 3] += x2 * w;
      acc[hh * 5 + 4] += w;
    }
  }

  // reduce over es low bits (lane bits 4,5)
#pragma unroll
  for (int k = 0; k < 24; ++k) {
    acc[k] += __shfl_xor(acc[k], 16);
    acc[k] += __shfl_xor(acc[k], 32);
  }
  if ((t & 48) == 0) {
    const int w = t >> 6;          // 0..7
    float* p = &s_part[w][jl][0];
#pragma unroll
    for (int k = 0; k < 24; ++k) p[k] = acc[k];
  }
  __syncthreads();

  // record layout: k = h*5+c for h<8 (0..39), raw sums at 40..43
  const size_t base = (((size_t)(jt * 32 + b)) * 2 + eq) * 704;
  if (t < 16) {
#pragma unroll
    for (int k = 0; k < 20; ++k) {
      float s = s_part[0][t][k] + s_part[1][t][k] + s_part[2][t][k] + s_part[3][t][k];
      pws[base + k * 16 + t] = s;
    }
#pragma unroll
    for (int c = 0; c < 4; ++c) {
      float s = s_part[0][t][20 + c] + s_part[1][t][20 + c] +
                s_part[2][t][20 + c] + s_part[3][t][20 + c];
      pws[base + (40 + c) * 16 + t] = s;
    }
  } else if (t >= 256 && t < 272) {
    const int l = t & 15;
#pragma unroll
    for (int k = 0; k < 20; ++k) {
      float s = s_part[4][l][k] + s_part[5][l][k] + s_part[6][l][k] + s_part[7][l][k];
      pws[base + (20 + k) * 16 + l] = s;
    }
  }
  __syncthreads();   // drains the pws stores (vmcnt(0) before barrier)

  // ---- fan-in: last arriver of the (jt,b) pair finalizes
  if (t == 0) {
    __threadfence();                       // publish pws (device scope)
    const int old = atomicAdd(&cnt[jt * 32 + b], 1);
    s_go = (old == 1);
  }
  __syncthreads();
  if (!s_go) return;
  __threadfence();                         // acquire partner's pws writes

  // reduce the 2 eq records into s_part (reuse as [44][16] scratch)
  float* s_tot = &s_part[0][0][0];         // 704 floats needed, have 3200
  const size_t base2 = ((size_t)(jt * 32 + b)) * 1408;
  for (int i = t; i < 704; i += 512)
    s_tot[i] = pws[base2 + i] + pws[base2 + 704 + i];
  __syncthreads();

  if (t < 16) {
    float tot[44];
#pragma unroll
    for (int k = 0; k < 44; ++k) tot[k] = s_tot[k * 16 + t];
    const float m0 = tot[40] * (1.f / 256.f), m1 = tot[41] * (1.f / 256.f);
    const float m2 = tot[42] * (1.f / 256.f), m3 = tot[43] * (1.f / 256.f);
    const float inv = 0.17677669529663687f;  // 1/sqrt(32)
    float am0 = 0.f, am1 = 0.f, am2 = 0.f, am3 = 0.f;
#pragma unroll
    for (int h = 0; h < 8; ++h) {
      const float dO = tot[h * 5 + 4];
      const float s0 = (tot[h * 5 + 0] - m0 * dO) * inv;
      const float s1 = (tot[h * 5 + 1] - m1 * dO) * inv;
      const float s2 = (tot[h * 5 + 2] - m2 * dO) * inv;
      const float s3 = (tot[h * 5 + 3] - m3 * dO) * inv;
      const float mx = fmaxf(fmaxf(s0, s1), fmaxf(s2, s3));
      const float e0 = expf(s0 - mx), e1 = expf(s1 - mx);
      const float e2 = expf(s2 - mx), e3 = expf(s3 - mx);
      const float r = 1.f / (e0 + e1 + e2 + e3);
      am0 += e0 * r; am1 += e1 * r; am2 += e2 * r; am3 += e3 * r;
    }
    s_a[t][0] = am0 * 0.125f; s_a[t][1] = am1 * 0.125f;
    s_a[t][2] = am2 * 0.125f; s_a[t][3] = am3 * 0.125f;
  }
  __syncthreads();

  // ---- out0[b][e][256+j]
  {
    const int jl2 = t & 15;
    const int er = t >> 4;         // 0..31
    const float a0 = s_a[jl2][0], a1 = s_a[jl2][1];
    const float a2 = s_a[jl2][2], a3 = s_a[jl2][3];
    const int jj = jt * 16 + jl2;
#pragma unroll
    for (int k = 0; k < 8; ++k) {
      const int e = er + 32 * k;
      const size_t idxS = ((size_t)(b * 256 + e)) * 512 + 256 + jj;
      const size_t idxO = ((size_t)(b * 256 + e)) * 256 + jj;
      out0[idxS] = a0 * state[idxS] + a1 * o0[idxO] + a2 * o1[idxO] + a3 * o2[idxO];
    }
  }

  // ---- out1 rows q = 256+j (4 sparse values, rest zero)
  {
    const int r = t >> 5;          // 0..15 (row within tile)
    const int c = t & 31;
    const int j3 = jt * 16 + r;
    const int q = 256 + j3;
    const int comp = j3 & 3;
    const int tc0 = (256 + j3) >> 2, tc1 = (512 + j3) >> 2;
    const int tc2 = (768 + j3) >> 2, tc3 = (1024 + j3) >> 2;
    const float av0 = s_a[r][0], av1 = s_a[r][1];
    const float av2 = s_a[r][2], av3 = s_a[r][3];
    float4* orow = (float4*)(out1 + ((size_t)(b * 512 + q)) * 1280);
#pragma unroll
    for (int k = 0; k < 10; ++k) {
      const int c4 = c + 32 * k;
      float4 o = make_float4(0.f, 0.f, 0.f, 0.f);
      float val = 0.f; bool hit = false;
      if (c4 == tc0)      { val = av0; hit = true; }
      else if (c4 == tc1) { val = av1; hit = true; }
      else if (c4 == tc2) { val = av2; hit = true; }
      else if (c4 == tc3) { val = av3; hit = true; }
      if (hit) {
        if (comp == 0) o.x = val; else if (comp == 1) o.y = val;
        else if (comp == 2) o.z = val; else o.w = val;
      }
      orow[c4] = o;
    }
  }
}

extern "C" void kernel_launch(void* const* d_in, const int* in_sizes, int n_in,
                              void* d_out, int out_size, void* d_ws, size_t ws_size,
                              hipStream_t stream) {
  const float* state = (const float*)d_in[0];
  const float* obs0  = (const float*)d_in[1];
  const float* obs1  = (const float*)d_in[2];
  const float* obs2  = (const float*)d_in[3];
  const float* Q     = (const float*)d_in[4];
  const float* Wq    = (const float*)d_in[5];
  const float* bq    = (const float*)d_in[6];
  const float* Wk    = (const float*)d_in[7];
  // d_in[8] = bk: cancels in the 4-way softmax (shift invariance), unused.

  float* out0 = (float*)d_out;                       // new_state [32,256,512]
  float* out1 = out0 + (size_t)32 * 256 * 512;       // atten [32,512,1280]

  float* ws  = (float*)d_ws;
  float* u   = ws;              // 65536
  float* v   = u + 65536;       // 8192
  float* wu2 = v + 8192;        // 524288
  float* wv  = wu2 + 524288;    // 65536
  float* pws = wv + 65536;      // 720896 (16*32*2*704)
  int*   cnt = (int*)(pws + 720896);  // 512 ints

  hipMemsetAsync(cnt, 0, 512 * sizeof(int), stream);
  k_uv_copy<<<1312, 256, 0, stream>>>(Q, Wq, bq, state, u, v, out0);
  k_w_onehot<<<1536, 256, 0, stream>>>(Wk, u, v, wu2, wv, out1);
  k_dotfin<<<dim3(16, 2, 32), 512, 0, stream>>>(state, obs0, obs1, obs2, wu2, wv,
                                                pws, cnt, out0, out1);
}

// Round 14
// 73.993 us; speedup vs baseline: 2.9576x; 2.9576x over previous
//
#include <hip/hip_runtime.h>
#include <math.h>

// Problem constants: bs=32, en=256, dx=512, dz=256, heads=8, dh=32, L=1280.
//
// Mask is block-diagonal eyes: q<256 -> one-hot row; q=256+j -> exactly 4
// nonzeros {q, 512+j, 768+j, 1024+j}. Wk folded into the query side; pe-dot
// and bk-dot are constant across the 4 softmax candidates -> cancel.
// Needed per (b,j,h):  dR_m = sum_e raw_m*w,  dO = sum_e w,
// with w = wu[j,h,e] + wv[b,h,e].
//
// Pipeline (4 launches), a-independent streaming packed into early launches:
//   L1 k_uv_copy : u,v projections (288 blks) || out0 state-copy (1024 blks)
//   L2 k_w_onehot: wu2,wv (512 blks)          || out1 one-hot rows (1024 blks)
//   L3 k_dot     : e split 4-ways (2048 blks, 32.2 KB LDS -> 3 blks/CU,
//                  ~24 waves/CU; 16 wu2 loads/thread) -> 4 partial records
//   L4 k_outA    : reduce 4 records + softmax + dependent output writes
//
// ws layout (floats): u[256][256]@0, v[32][256]@65536, wu2[8][256e][256j]@73728,
// wv[32][8][256e]@598016, pws[16jt][32b][4eq][44k][16jl]@663552 (1441792).

// ---------------------------------------------------------------- k_uv_copy
__global__ __launch_bounds__(256)
void k_uv_copy(const float* __restrict__ Q, const float* __restrict__ Wq,
               const float* __restrict__ bq, const float* __restrict__ state,
               float* __restrict__ u, float* __restrict__ v,
               float* __restrict__ out0) {
  const int blk = blockIdx.x;
  const int t = threadIdx.x;
  if (blk < 288) {
    __shared__ float row[256];
    float rv;
    if (blk < 256) {
      rv = Q[(256 + blk) * 256 + t];
    } else {
      const int b = blk - 256;
      // sinusoidal PE over the BATCH axis (faithful quirk): pos=b, d_model=256
      const float dv = expf(-9.210340371976184f * (float)((t >> 1) << 1) * (1.0f / 256.0f));
      const float ang = (float)b * dv;
      rv = (t & 1) ? cosf(ang) : sinf(ang);
    }
    row[t] = rv;
    __syncthreads();
    float acc = (blk < 256) ? 0.0f : bq[t];
    for (int e = 0; e < 256; ++e) acc += row[e] * Wq[e * 256 + t];
    if (blk < 256) u[blk * 256 + t] = acc;
    else           v[(blk - 256) * 256 + t] = acc;
  } else {
    // role B: copy q<256 half of out0 (8 e-rows x 256 cols per block)
    const int id = blk - 288;      // 0..1023
    const int b = id >> 5, eg = id & 31;
    const int r = t >> 5;          // 0..7
    const int c = t & 31;          // 0..31 (float4 col)
    const int e = eg * 8 + r;
    const size_t base = ((size_t)(b * 256 + e)) * 512;
    *(float4*)(out0 + base + c * 4)        = *(const float4*)(state + base + c * 4);
    *(float4*)(out0 + base + (c + 32) * 4) = *(const float4*)(state + base + (c + 32) * 4);
  }
}

// ---------------------------------------------------------------- k_w_onehot
__global__ __launch_bounds__(256)
void k_w_onehot(const float* __restrict__ Wk, const float* __restrict__ u,
                const float* __restrict__ v, float* __restrict__ wu2,
                float* __restrict__ wv, float* __restrict__ out1) {
  const int blk = blockIdx.x;
  const int t = threadIdx.x;
  if (blk < 512) {
    const int e = blk & 255;
    const int part = blk >> 8;     // 0 -> wu2, 1 -> wv
    __shared__ float wrow[256];
    wrow[t] = Wk[e * 256 + t];
    __syncthreads();
    if (part == 0) {
      const float* ur = u + t * 256;
#pragma unroll
      for (int h = 0; h < 8; ++h) {
        float acc = 0.0f;
#pragma unroll
        for (int d = 0; d < 32; ++d) acc += ur[h * 32 + d] * wrow[h * 32 + d];
        wu2[(h * 256 + e) * 256 + t] = acc;
      }
    } else if (t < 32) {
      const float* vr = v + t * 256;
#pragma unroll
      for (int h = 0; h < 8; ++h) {
        float acc = 0.0f;
#pragma unroll
        for (int d = 0; d < 32; ++d) acc += vr[h * 32 + d] * wrow[h * 32 + d];
        wv[(t * 8 + h) * 256 + e] = acc;
      }
    }
  } else {
    // role C: out1 one-hot rows q<256 (8 rows per block, 320 float4 per row)
    const int id = blk - 512;      // 0..1023
    const int b = id >> 5, qg = id & 31;
#pragma unroll
    for (int k = 0; k < 8; ++k) {
      const int q = qg * 8 + k;
      float4* row = (float4*)(out1 + ((size_t)(b * 512 + q)) * 1280);
      float4 o = make_float4(0.f, 0.f, 0.f, 0.f);
      if (t == (q >> 2)) {
        const int comp = q & 3;
        if (comp == 0) o.x = 1.f; else if (comp == 1) o.y = 1.f;
        else if (comp == 2) o.z = 1.f; else o.w = 1.f;
      }
      row[t] = o;
      if (t < 64) row[256 + t] = make_float4(0.f, 0.f, 0.f, 0.f);
    }
  }
}

// ---------------------------------------------------------------- k_dot
// grid (16 jt, 4 eq, 32 b), 512 threads = 8 waves. Per block: 64 e's.
// Stage s_data[4][64][17] (2 float4 loads/thread) + s_wv[512] (1 load).
// Compute: t = jl(0..15)+16*es(0..15)+256*hp(0..1); el = it*16+es so each
// LDS read instruction hits banks (17u+jl) mod 32 -> uniform 2-way (free).
// 16 wu2 global loads/thread (L2-resident). Reduce: shfl(16,32) -> LDS
// across 8 waves -> [44][16] partial record (4 records per (jt,b)).
__global__ __launch_bounds__(512)
void k_dot(const float* __restrict__ state, const float* __restrict__ o0,
           const float* __restrict__ o1, const float* __restrict__ o2,
           const float* __restrict__ wu2, const float* __restrict__ wv,
           float* __restrict__ pws) {
  const int t = threadIdx.x;
  const int jt = blockIdx.x;       // 0..15
  const int eq = blockIdx.y;       // 0..3
  const int b  = blockIdx.z;       // 0..31

  __shared__ float s_data[4][64][17];  // 17.4 KB
  __shared__ float s_wv[512];          //  2.0 KB
  __shared__ float s_part[8][16][25];  // 12.8 KB   (total ~32.2 KB)

  // ---- stage data tile: 1024 float4 cells, 2 per thread
#pragma unroll
  for (int rep = 0; rep < 2; ++rep) {
    const int c = t + rep * 512;   // 0..1023
    const int m = c >> 8;          // 0..3
    const int r = c & 255;
    const int e = r >> 2;          // 0..63
    const int jq = r & 3;          // 0..3
    const int ge = eq * 64 + e;    // global e
    const int j0 = jt * 16 + jq * 4;
    const float* src;
    if (m == 0)      src = state + ((size_t)(b * 256 + ge)) * 512 + 256 + j0;
    else if (m == 1) src = o0 + ((size_t)(b * 256 + ge)) * 256 + j0;
    else if (m == 2) src = o1 + ((size_t)(b * 256 + ge)) * 256 + j0;
    else             src = o2 + ((size_t)(b * 256 + ge)) * 256 + j0;
    const float4 v4 = *(const float4*)src;
    const int jb = jq * 4;
    s_data[m][e][jb]   = v4.x; s_data[m][e][jb+1] = v4.y;
    s_data[m][e][jb+2] = v4.z; s_data[m][e][jb+3] = v4.w;
  }
  // ---- stage wv slice [h][64]: one float per thread
  s_wv[t & 511] = wv[b * 2048 + ((t & 511) >> 6) * 256 + eq * 64 + (t & 63)];
  __syncthreads();

  const int jl = t & 15;
  const int es = (t >> 4) & 15;    // 0..15
  const int hp = t >> 8;           // 0..1
  const int j = jt * 16 + jl;

  // acc[hh*5+c]: c=0..3 dR(state,o0,o1,o2), c=4 dO(ones); 20..23 raw sums
  float acc[24];
#pragma unroll
  for (int k = 0; k < 24; ++k) acc[k] = 0.f;

  const float* pwu = wu2 + (size_t)hp * 4 * 256 * 256 + j;  // + (hh*256+e)*256
  const float* pwv = s_wv + hp * 4 * 64;                    // + hh*64+el

#pragma unroll
  for (int it = 0; it < 4; ++it) {
    const int el = it * 16 + es;   // 0..63 within this eq slice
    const int e = eq * 64 + el;    // global e
    const float s  = s_data[0][el][jl];
    const float x0 = s_data[1][el][jl];
    const float x1 = s_data[2][el][jl];
    const float x2 = s_data[3][el][jl];
    acc[20] += s; acc[21] += x0; acc[22] += x1; acc[23] += x2;
#pragma unroll
    for (int hh = 0; hh < 4; ++hh) {
      const float w = pwu[(size_t)(hh * 256 + e) * 256] + pwv[hh * 64 + el];
      acc[hh * 5 + 0] += s * w;  acc[hh * 5 + 1] += x0 * w;
      acc[hh * 5 + 2] += x1 * w; acc[hh * 5 + 3] += x2 * w;
      acc[hh * 5 + 4] += w;
    }
  }

  // reduce over es low bits (lane bits 4,5)
#pragma unroll
  for (int k = 0; k < 24; ++k) {
    acc[k] += __shfl_xor(acc[k], 16);
    acc[k] += __shfl_xor(acc[k], 32);
  }
  if ((t & 48) == 0) {
    const int w = t >> 6;          // 0..7
    float* p = &s_part[w][jl][0];
#pragma unroll
    for (int k = 0; k < 24; ++k) p[k] = acc[k];
  }
  __syncthreads();

  // record layout: k = h*5+c for h<8 (0..39), raw sums at 40..43
  const size_t base = (((size_t)(jt * 32 + b)) * 4 + eq) * 704;
  if (t < 16) {
#pragma unroll
    for (int k = 0; k < 20; ++k) {
      float s = s_part[0][t][k] + s_part[1][t][k] + s_part[2][t][k] + s_part[3][t][k];
      pws[base + k * 16 + t] = s;
    }
#pragma unroll
    for (int c = 0; c < 4; ++c) {
      float s = s_part[0][t][20 + c] + s_part[1][t][20 + c] +
                s_part[2][t][20 + c] + s_part[3][t][20 + c];
      pws[base + (40 + c) * 16 + t] = s;
    }
  } else if (t >= 256 && t < 272) {
    const int l = t & 15;
#pragma unroll
    for (int k = 0; k < 20; ++k) {
      float s = s_part[4][l][k] + s_part[5][l][k] + s_part[6][l][k] + s_part[7][l][k];
      pws[base + (20 + k) * 16 + l] = s;
    }
  }
}

// ---------------------------------------------------------------- k_outA
// 512 blocks (jt,b): sum 4 eq-partials, softmax (16 lanes), then write
// out0 cols 256+j and out1 sparse rows q=256+j.
__global__ __launch_bounds__(512)
void k_outA(const float* __restrict__ state, const float* __restrict__ o0,
            const float* __restrict__ o1, const float* __restrict__ o2,
            const float* __restrict__ pws, float* __restrict__ out0,
            float* __restrict__ out1) {
  const int blk = blockIdx.x;
  const int t = threadIdx.x;
  const int jt = blk & 15;
  const int b  = blk >> 4;
  __shared__ float s_tot[704];     // [44k][16jl] flat
  __shared__ float s_a[16][4];

  const size_t base = ((size_t)(jt * 32 + b)) * 2816;  // 4 records of 704
  for (int i = t; i < 704; i += 512)
    s_tot[i] = (pws[base + i] + pws[base + 704 + i]) +
               (pws[base + 1408 + i] + pws[base + 2112 + i]);
  __syncthreads();

  if (t < 16) {
    float tot[44];
#pragma unroll
    for (int k = 0; k < 44; ++k) tot[k] = s_tot[k * 16 + t];
    const float m0 = tot[40] * (1.f / 256.f), m1 = tot[41] * (1.f / 256.f);
    const float m2 = tot[42] * (1.f / 256.f), m3 = tot[43] * (1.f / 256.f);
    const float inv = 0.17677669529663687f;  // 1/sqrt(32)
    float am0 = 0.f, am1 = 0.f, am2 = 0.f, am3 = 0.f;
#pragma unroll
    for (int h = 0; h < 8; ++h) {
      const float dO = tot[h * 5 + 4];
      const float s0 = (tot[h * 5 + 0] - m0 * dO) * inv;
      const float s1 = (tot[h * 5 + 1] - m1 * dO) * inv;
      const float s2 = (tot[h * 5 + 2] - m2 * dO) * inv;
      const float s3 = (tot[h * 5 + 3] - m3 * dO) * inv;
      const float mx = fmaxf(fmaxf(s0, s1), fmaxf(s2, s3));
      const float e0 = expf(s0 - mx), e1 = expf(s1 - mx);
      const float e2 = expf(s2 - mx), e3 = expf(s3 - mx);
      const float r = 1.f / (e0 + e1 + e2 + e3);
      am0 += e0 * r; am1 += e1 * r; am2 += e2 * r; am3 += e3 * r;
    }
    s_a[t][0] = am0 * 0.125f; s_a[t][1] = am1 * 0.125f;
    s_a[t][2] = am2 * 0.125f; s_a[t][3] = am3 * 0.125f;
  }
  __syncthreads();

  // ---- out0[b][e][256+j]
  {
    const int jl2 = t & 15;
    const int er = t >> 4;         // 0..31
    const float a0 = s_a[jl2][0], a1 = s_a[jl2][1];
    const float a2 = s_a[jl2][2], a3 = s_a[jl2][3];
    const int jj = jt * 16 + jl2;
#pragma unroll
    for (int k = 0; k < 8; ++k) {
      const int e = er + 32 * k;
      const size_t idxS = ((size_t)(b * 256 + e)) * 512 + 256 + jj;
      const size_t idxO = ((size_t)(b * 256 + e)) * 256 + jj;
      out0[idxS] = a0 * state[idxS] + a1 * o0[idxO] + a2 * o1[idxO] + a3 * o2[idxO];
    }
  }

  // ---- out1 rows q = 256+j (4 sparse values, rest zero)
  {
    const int r = t >> 5;          // 0..15 (row within tile)
    const int c = t & 31;
    const int j3 = jt * 16 + r;
    const int q = 256 + j3;
    const int comp = j3 & 3;
    const int tc0 = (256 + j3) >> 2, tc1 = (512 + j3) >> 2;
    const int tc2 = (768 + j3) >> 2, tc3 = (1024 + j3) >> 2;
    const float av0 = s_a[r][0], av1 = s_a[r][1];
    const float av2 = s_a[r][2], av3 = s_a[r][3];
    float4* orow = (float4*)(out1 + ((size_t)(b * 512 + q)) * 1280);
#pragma unroll
    for (int k = 0; k < 10; ++k) {
      const int c4 = c + 32 * k;
      float4 o = make_float4(0.f, 0.f, 0.f, 0.f);
      float val = 0.f; bool hit = false;
      if (c4 == tc0)      { val = av0; hit = true; }
      else if (c4 == tc1) { val = av1; hit = true; }
      else if (c4 == tc2) { val = av2; hit = true; }
      else if (c4 == tc3) { val = av3; hit = true; }
      if (hit) {
        if (comp == 0) o.x = val; else if (comp == 1) o.y = val;
        else if (comp == 2) o.z = val; else o.w = val;
      }
      orow[c4] = o;
    }
  }
}

extern "C" void kernel_launch(void* const* d_in, const int* in_sizes, int n_in,
                              void* d_out, int out_size, void* d_ws, size_t ws_size,
                              hipStream_t stream) {
  const float* state = (const float*)d_in[0];
  const float* obs0  = (const float*)d_in[1];
  const float* obs1  = (const float*)d_in[2];
  const float* obs2  = (const float*)d_in[3];
  const float* Q     = (const float*)d_in[4];
  const float* Wq    = (const float*)d_in[5];
  const float* bq    = (const float*)d_in[6];
  const float* Wk    = (const float*)d_in[7];
  // d_in[8] = bk: cancels in the 4-way softmax (shift invariance), unused.

  float* out0 = (float*)d_out;                       // new_state [32,256,512]
  float* out1 = out0 + (size_t)32 * 256 * 512;       // atten [32,512,1280]

  float* ws  = (float*)d_ws;
  float* u   = ws;              // 65536
  float* v   = u + 65536;       // 8192
  float* wu2 = v + 8192;        // 524288
  float* wv  = wu2 + 524288;    // 65536
  float* pws = wv + 65536;      // 1441792 (16*32*4*704)

  k_uv_copy<<<1312, 256, 0, stream>>>(Q, Wq, bq, state, u, v, out0);
  k_w_onehot<<<1536, 256, 0, stream>>>(Wk, u, v, wu2, wv, out1);
  k_dot<<<dim3(16, 4, 32), 512, 0, stream>>>(state, obs0, obs1, obs2, wu2, wv, pws);
  k_outA<<<512, 512, 0, stream>>>(state, obs0, obs1, obs2, pws, out0, out1);
}

// Round 15
// 67.282 us; speedup vs baseline: 3.2526x; 1.0998x over previous
//
#include <hip/hip_runtime.h>
#include <math.h>

// Problem constants: bs=32, en=256, dx=512, dz=256, heads=8, dh=32, L=1280.
//
// Mask is block-diagonal eyes: q<256 -> one-hot row; q=256+j -> exactly 4
// nonzeros {q, 512+j, 768+j, 1024+j}. Wk folded into the query side; pe-dot
// and bk-dot are constant across the 4 softmax candidates -> cancel.
// Needed per (b,j,h):  dR_m = sum_e raw_m*w,  dO = sum_e w,
// with w = wu[j,h,e] + wv[b,h,e].
//
// KEY FIX this round: k_w previously read u with each lane walking a private
// 1KB row (stride-1KB across lanes) -> 64 distinct 64B L2 lines per load
// instruction -> ~1 GB of L2 traffic (~30us at 34.5 TB/s), invisible in HBM
// counters. k_uv now scatter-stores the TRANSPOSED uT[f][j] / vT[f][b]
// (one scalar store per thread, ~4MB once) so k_w reads are lane-coalesced.
//
// Pipeline (4 launches), a-independent streaming packed into early launches:
//   L1 k_uv_copy : uT,vT projections (288 blks) || out0 state-copy (1024)
//   L2 k_w_onehot: wu2,wv (512 blks, coalesced) || out1 one-hot rows (1024)
//   L3 k_dot     : e split 4-ways (2048 blks, 32.2 KB LDS, 3 blks/CU)
//   L4 k_outA    : reduce 4 records + softmax + dependent output writes
//
// ws layout (floats): uT[256f][256j]@0, vT[256f][32b]@65536,
// wu2[8][256e][256j]@73728, wv[32][8][256e]@598016,
// pws[16jt][32b][4eq][44k][16jl]@663552 (1441792).

// ---------------------------------------------------------------- k_uv_copy
__global__ __launch_bounds__(256)
void k_uv_copy(const float* __restrict__ Q, const float* __restrict__ Wq,
               const float* __restrict__ bq, const float* __restrict__ state,
               float* __restrict__ uT, float* __restrict__ vT,
               float* __restrict__ out0) {
  const int blk = blockIdx.x;
  const int t = threadIdx.x;
  if (blk < 288) {
    __shared__ float row[256];
    float rv;
    if (blk < 256) {
      rv = Q[(256 + blk) * 256 + t];
    } else {
      const int b = blk - 256;
      // sinusoidal PE over the BATCH axis (faithful quirk): pos=b, d_model=256
      const float dv = expf(-9.210340371976184f * (float)((t >> 1) << 1) * (1.0f / 256.0f));
      const float ang = (float)b * dv;
      rv = (t & 1) ? cosf(ang) : sinf(ang);
    }
    row[t] = rv;
    __syncthreads();
    float acc = (blk < 256) ? 0.0f : bq[t];
    for (int e = 0; e < 256; ++e) acc += row[e] * Wq[e * 256 + t];
    // transposed scatter store (uncoalesced but tiny: 1 store/thread)
    if (blk < 256) uT[t * 256 + blk] = acc;
    else           vT[t * 32 + (blk - 256)] = acc;
  } else {
    // role B: copy q<256 half of out0 (8 e-rows x 256 cols per block)
    const int id = blk - 288;      // 0..1023
    const int b = id >> 5, eg = id & 31;
    const int r = t >> 5;          // 0..7
    const int c = t & 31;          // 0..31 (float4 col)
    const int e = eg * 8 + r;
    const size_t base = ((size_t)(b * 256 + e)) * 512;
    *(float4*)(out0 + base + c * 4)        = *(const float4*)(state + base + c * 4);
    *(float4*)(out0 + base + (c + 32) * 4) = *(const float4*)(state + base + (c + 32) * 4);
  }
}

// ---------------------------------------------------------------- k_w_onehot
// blk <  256 : wu2[h][e][j] = sum_d uT[h*32+d][j] * wrow[h*32+d]  (coalesced)
// blk <  512 : wv[b][h][e]  = sum_d vT[h*32+d][b] * wrow[h*32+d]  (coalesced)
// blk >= 512 : out1 one-hot rows q<256 (a-independent streaming)
__global__ __launch_bounds__(256)
void k_w_onehot(const float* __restrict__ Wk, const float* __restrict__ uT,
                const float* __restrict__ vT, float* __restrict__ wu2,
                float* __restrict__ wv, float* __restrict__ out1) {
  const int blk = blockIdx.x;
  const int t = threadIdx.x;
  if (blk < 512) {
    const int e = blk & 255;
    const int part = blk >> 8;     // 0 -> wu2, 1 -> wv
    __shared__ float wrow[256];
    wrow[t] = Wk[e * 256 + t];
    __syncthreads();
    if (part == 0) {
      // thread t = j; lane-coalesced uT reads
#pragma unroll
      for (int h = 0; h < 8; ++h) {
        float acc = 0.0f;
#pragma unroll
        for (int d = 0; d < 32; ++d)
          acc += uT[(h * 32 + d) * 256 + t] * wrow[h * 32 + d];
        wu2[(h * 256 + e) * 256 + t] = acc;
      }
    } else if (t < 32) {
      // thread t = b; lane-coalesced vT reads (32 lanes x 4B)
#pragma unroll
      for (int h = 0; h < 8; ++h) {
        float acc = 0.0f;
#pragma unroll
        for (int d = 0; d < 32; ++d)
          acc += vT[(h * 32 + d) * 32 + t] * wrow[h * 32 + d];
        wv[(t * 8 + h) * 256 + e] = acc;
      }
    }
  } else {
    // role C: out1 one-hot rows q<256 (8 rows per block, 320 float4 per row)
    const int id = blk - 512;      // 0..1023
    const int b = id >> 5, qg = id & 31;
#pragma unroll
    for (int k = 0; k < 8; ++k) {
      const int q = qg * 8 + k;
      float4* row = (float4*)(out1 + ((size_t)(b * 512 + q)) * 1280);
      float4 o = make_float4(0.f, 0.f, 0.f, 0.f);
      if (t == (q >> 2)) {
        const int comp = q & 3;
        if (comp == 0) o.x = 1.f; else if (comp == 1) o.y = 1.f;
        else if (comp == 2) o.z = 1.f; else o.w = 1.f;
      }
      row[t] = o;
      if (t < 64) row[256 + t] = make_float4(0.f, 0.f, 0.f, 0.f);
    }
  }
}

// ---------------------------------------------------------------- k_dot
// grid (16 jt, 4 eq, 32 b), 512 threads = 8 waves (round-14 verbatim).
__global__ __launch_bounds__(512)
void k_dot(const float* __restrict__ state, const float* __restrict__ o0,
           const float* __restrict__ o1, const float* __restrict__ o2,
           const float* __restrict__ wu2, const float* __restrict__ wv,
           float* __restrict__ pws) {
  const int t = threadIdx.x;
  const int jt = blockIdx.x;       // 0..15
  const int eq = blockIdx.y;       // 0..3
  const int b  = blockIdx.z;       // 0..31

  __shared__ float s_data[4][64][17];  // 17.4 KB
  __shared__ float s_wv[512];          //  2.0 KB
  __shared__ float s_part[8][16][25];  // 12.8 KB   (total ~32.2 KB)

  // ---- stage data tile: 1024 float4 cells, 2 per thread
#pragma unroll
  for (int rep = 0; rep < 2; ++rep) {
    const int c = t + rep * 512;   // 0..1023
    const int m = c >> 8;          // 0..3
    const int r = c & 255;
    const int e = r >> 2;          // 0..63
    const int jq = r & 3;          // 0..3
    const int ge = eq * 64 + e;    // global e
    const int j0 = jt * 16 + jq * 4;
    const float* src;
    if (m == 0)      src = state + ((size_t)(b * 256 + ge)) * 512 + 256 + j0;
    else if (m == 1) src = o0 + ((size_t)(b * 256 + ge)) * 256 + j0;
    else if (m == 2) src = o1 + ((size_t)(b * 256 + ge)) * 256 + j0;
    else             src = o2 + ((size_t)(b * 256 + ge)) * 256 + j0;
    const float4 v4 = *(const float4*)src;
    const int jb = jq * 4;
    s_data[m][e][jb]   = v4.x; s_data[m][e][jb+1] = v4.y;
    s_data[m][e][jb+2] = v4.z; s_data[m][e][jb+3] = v4.w;
  }
  // ---- stage wv slice [h][64]: one float per thread
  s_wv[t & 511] = wv[b * 2048 + ((t & 511) >> 6) * 256 + eq * 64 + (t & 63)];
  __syncthreads();

  const int jl = t & 15;
  const int es = (t >> 4) & 15;    // 0..15
  const int hp = t >> 8;           // 0..1
  const int j = jt * 16 + jl;

  // acc[hh*5+c]: c=0..3 dR(state,o0,o1,o2), c=4 dO(ones); 20..23 raw sums
  float acc[24];
#pragma unroll
  for (int k = 0; k < 24; ++k) acc[k] = 0.f;

  const float* pwu = wu2 + (size_t)hp * 4 * 256 * 256 + j;  // + (hh*256+e)*256
  const float* pwv = s_wv + hp * 4 * 64;                    // + hh*64+el

#pragma unroll
  for (int it = 0; it < 4; ++it) {
    const int el = it * 16 + es;   // 0..63 within this eq slice
    const int e = eq * 64 + el;    // global e
    const float s  = s_data[0][el][jl];
    const float x0 = s_data[1][el][jl];
    const float x1 = s_data[2][el][jl];
    const float x2 = s_data[3][el][jl];
    acc[20] += s; acc[21] += x0; acc[22] += x1; acc[23] += x2;
#pragma unroll
    for (int hh = 0; hh < 4; ++hh) {
      const float w = pwu[(size_t)(hh * 256 + e) * 256] + pwv[hh * 64 + el];
      acc[hh * 5 + 0] += s * w;  acc[hh * 5 + 1] += x0 * w;
      acc[hh * 5 + 2] += x1 * w; acc[hh * 5 + 3] += x2 * w;
      acc[hh * 5 + 4] += w;
    }
  }

  // reduce over es low bits (lane bits 4,5)
#pragma unroll
  for (int k = 0; k < 24; ++k) {
    acc[k] += __shfl_xor(acc[k], 16);
    acc[k] += __shfl_xor(acc[k], 32);
  }
  if ((t & 48) == 0) {
    const int w = t >> 6;          // 0..7
    float* p = &s_part[w][jl][0];
#pragma unroll
    for (int k = 0; k < 24; ++k) p[k] = acc[k];
  }
  __syncthreads();

  // record layout: k = h*5+c for h<8 (0..39), raw sums at 40..43
  const size_t base = (((size_t)(jt * 32 + b)) * 4 + eq) * 704;
  if (t < 16) {
#pragma unroll
    for (int k = 0; k < 20; ++k) {
      float s = s_part[0][t][k] + s_part[1][t][k] + s_part[2][t][k] + s_part[3][t][k];
      pws[base + k * 16 + t] = s;
    }
#pragma unroll
    for (int c = 0; c < 4; ++c) {
      float s = s_part[0][t][20 + c] + s_part[1][t][20 + c] +
                s_part[2][t][20 + c] + s_part[3][t][20 + c];
      pws[base + (40 + c) * 16 + t] = s;
    }
  } else if (t >= 256 && t < 272) {
    const int l = t & 15;
#pragma unroll
    for (int k = 0; k < 20; ++k) {
      float s = s_part[4][l][k] + s_part[5][l][k] + s_part[6][l][k] + s_part[7][l][k];
      pws[base + (20 + k) * 16 + l] = s;
    }
  }
}

// ---------------------------------------------------------------- k_outA
// 512 blocks (jt,b): sum 4 eq-partials, softmax (16 lanes), then write
// out0 cols 256+j and out1 sparse rows q=256+j.
__global__ __launch_bounds__(512)
void k_outA(const float* __restrict__ state, const float* __restrict__ o0,
            const float* __restrict__ o1, const float* __restrict__ o2,
            const float* __restrict__ pws, float* __restrict__ out0,
            float* __restrict__ out1) {
  const int blk = blockIdx.x;
  const int t = threadIdx.x;
  const int jt = blk & 15;
  const int b  = blk >> 4;
  __shared__ float s_tot[704];     // [44k][16jl] flat
  __shared__ float s_a[16][4];

  const size_t base = ((size_t)(jt * 32 + b)) * 2816;  // 4 records of 704
  for (int i = t; i < 704; i += 512)
    s_tot[i] = (pws[base + i] + pws[base + 704 + i]) +
               (pws[base + 1408 + i] + pws[base + 2112 + i]);
  __syncthreads();

  if (t < 16) {
    float tot[44];
#pragma unroll
    for (int k = 0; k < 44; ++k) tot[k] = s_tot[k * 16 + t];
    const float m0 = tot[40] * (1.f / 256.f), m1 = tot[41] * (1.f / 256.f);
    const float m2 = tot[42] * (1.f / 256.f), m3 = tot[43] * (1.f / 256.f);
    const float inv = 0.17677669529663687f;  // 1/sqrt(32)
    float am0 = 0.f, am1 = 0.f, am2 = 0.f, am3 = 0.f;
#pragma unroll
    for (int h = 0; h < 8; ++h) {
      const float dO = tot[h * 5 + 4];
      const float s0 = (tot[h * 5 + 0] - m0 * dO) * inv;
      const float s1 = (tot[h * 5 + 1] - m1 * dO) * inv;
      const float s2 = (tot[h * 5 + 2] - m2 * dO) * inv;
      const float s3 = (tot[h * 5 + 3] - m3 * dO) * inv;
      const float mx = fmaxf(fmaxf(s0, s1), fmaxf(s2, s3));
      const float e0 = expf(s0 - mx), e1 = expf(s1 - mx);
      const float e2 = expf(s2 - mx), e3 = expf(s3 - mx);
      const float r = 1.f / (e0 + e1 + e2 + e3);
      am0 += e0 * r; am1 += e1 * r; am2 += e2 * r; am3 += e3 * r;
    }
    s_a[t][0] = am0 * 0.125f; s_a[t][1] = am1 * 0.125f;
    s_a[t][2] = am2 * 0.125f; s_a[t][3] = am3 * 0.125f;
  }
  __syncthreads();

  // ---- out0[b][e][256+j]
  {
    const int jl2 = t & 15;
    const int er = t >> 4;         // 0..31
    const float a0 = s_a[jl2][0], a1 = s_a[jl2][1];
    const float a2 = s_a[jl2][2], a3 = s_a[jl2][3];
    const int jj = jt * 16 + jl2;
#pragma unroll
    for (int k = 0; k < 8; ++k) {
      const int e = er + 32 * k;
      const size_t idxS = ((size_t)(b * 256 + e)) * 512 + 256 + jj;
      const size_t idxO = ((size_t)(b * 256 + e)) * 256 + jj;
      out0[idxS] = a0 * state[idxS] + a1 * o0[idxO] + a2 * o1[idxO] + a3 * o2[idxO];
    }
  }

  // ---- out1 rows q = 256+j (4 sparse values, rest zero)
  {
    const int r = t >> 5;          // 0..15 (row within tile)
    const int c = t & 31;
    const int j3 = jt * 16 + r;
    const int q = 256 + j3;
    const int comp = j3 & 3;
    const int tc0 = (256 + j3) >> 2, tc1 = (512 + j3) >> 2;
    const int tc2 = (768 + j3) >> 2, tc3 = (1024 + j3) >> 2;
    const float av0 = s_a[r][0], av1 = s_a[r][1];
    const float av2 = s_a[r][2], av3 = s_a[r][3];
    float4* orow = (float4*)(out1 + ((size_t)(b * 512 + q)) * 1280);
#pragma unroll
    for (int k = 0; k < 10; ++k) {
      const int c4 = c + 32 * k;
      float4 o = make_float4(0.f, 0.f, 0.f, 0.f);
      float val = 0.f; bool hit = false;
      if (c4 == tc0)      { val = av0; hit = true; }
      else if (c4 == tc1) { val = av1; hit = true; }
      else if (c4 == tc2) { val = av2; hit = true; }
      else if (c4 == tc3) { val = av3; hit = true; }
      if (hit) {
        if (comp == 0) o.x = val; else if (comp == 1) o.y = val;
        else if (comp == 2) o.z = val; else o.w = val;
      }
      orow[c4] = o;
    }
  }
}

extern "C" void kernel_launch(void* const* d_in, const int* in_sizes, int n_in,
                              void* d_out, int out_size, void* d_ws, size_t ws_size,
                              hipStream_t stream) {
  const float* state = (const float*)d_in[0];
  const float* obs0  = (const float*)d_in[1];
  const float* obs1  = (const float*)d_in[2];
  const float* obs2  = (const float*)d_in[3];
  const float* Q     = (const float*)d_in[4];
  const float* Wq    = (const float*)d_in[5];
  const float* bq    = (const float*)d_in[6];
  const float* Wk    = (const float*)d_in[7];
  // d_in[8] = bk: cancels in the 4-way softmax (shift invariance), unused.

  float* out0 = (float*)d_out;                       // new_state [32,256,512]
  float* out1 = out0 + (size_t)32 * 256 * 512;       // atten [32,512,1280]

  float* ws  = (float*)d_ws;
  float* uT  = ws;              // 65536  [256f][256j]
  float* vT  = uT + 65536;      // 8192   [256f][32b]
  float* wu2 = vT + 8192;       // 524288
  float* wv  = wu2 + 524288;    // 65536
  float* pws = wv + 65536;      // 1441792 (16*32*4*704)

  k_uv_copy<<<1312, 256, 0, stream>>>(Q, Wq, bq, state, uT, vT, out0);
  k_w_onehot<<<1536, 256, 0, stream>>>(Wk, uT, vT, wu2, wv, out1);
  k_dot<<<dim3(16, 4, 32), 512, 0, stream>>>(state, obs0, obs1, obs2, wu2, wv, pws);
  k_outA<<<512, 512, 0, stream>>>(state, obs0, obs1, obs2, pws, out0, out1);
}

// Round 16
// 63.890 us; speedup vs baseline: 3.4253x; 1.0531x over previous
//
#include <hip/hip_runtime.h>
#include <math.h>

// Problem constants: bs=32, en=256, dx=512, dz=256, heads=8, dh=32, L=1280.
//
// Mask is block-diagonal eyes: q<256 -> one-hot row; q=256+j -> exactly 4
// nonzeros {q, 512+j, 768+j, 1024+j}. Wk folded into the query side; pe-dot
// and bk-dot are constant across the 4 softmax candidates -> cancel.
// Needed per (b,j,h):  dR_m = sum_e raw_m*w,  dO = sum_e w,
// with w = wu[j,h,e] + wv[b,h,e].
//
// Pipeline (3 launches):
//   L1 k_uv_copy : uT,vT projections (288 blks) || out0 state-copy (1024)
//   L2 k_w_onehot: wu2,wv (512 blks, coalesced) || out1 one-hot rows (1024)
//   L3 k_all     : 512 blocks (jt,b) = 2/CU FULLY RESIDENT. Per block:
//                  dot over 256 e in 2 LDS-staged chunks of 128 -> in-LDS
//                  reduce -> softmax -> dependent out0 cols / out1 rows.
//                  No pws, no 4th launch; output stores overlap dot compute
//                  across blocks.
//
// ws layout (floats): uT[256f][256j]@0, vT[256f][32b]@65536,
// wu2[8][256e][256j]@73728, wv[32][8][256e]@598016.

// ---------------------------------------------------------------- k_uv_copy
__global__ __launch_bounds__(256)
void k_uv_copy(const float* __restrict__ Q, const float* __restrict__ Wq,
               const float* __restrict__ bq, const float* __restrict__ state,
               float* __restrict__ uT, float* __restrict__ vT,
               float* __restrict__ out0) {
  const int blk = blockIdx.x;
  const int t = threadIdx.x;
  if (blk < 288) {
    __shared__ float row[256];
    float rv;
    if (blk < 256) {
      rv = Q[(256 + blk) * 256 + t];
    } else {
      const int b = blk - 256;
      // sinusoidal PE over the BATCH axis (faithful quirk): pos=b, d_model=256
      const float dv = expf(-9.210340371976184f * (float)((t >> 1) << 1) * (1.0f / 256.0f));
      const float ang = (float)b * dv;
      rv = (t & 1) ? cosf(ang) : sinf(ang);
    }
    row[t] = rv;
    __syncthreads();
    float acc = (blk < 256) ? 0.0f : bq[t];
    for (int e = 0; e < 256; ++e) acc += row[e] * Wq[e * 256 + t];
    // transposed scatter store (uncoalesced but tiny: 1 store/thread)
    if (blk < 256) uT[t * 256 + blk] = acc;
    else           vT[t * 32 + (blk - 256)] = acc;
  } else {
    // role B: copy q<256 half of out0 (8 e-rows x 256 cols per block)
    const int id = blk - 288;      // 0..1023
    const int b = id >> 5, eg = id & 31;
    const int r = t >> 5;          // 0..7
    const int c = t & 31;          // 0..31 (float4 col)
    const int e = eg * 8 + r;
    const size_t base = ((size_t)(b * 256 + e)) * 512;
    *(float4*)(out0 + base + c * 4)        = *(const float4*)(state + base + c * 4);
    *(float4*)(out0 + base + (c + 32) * 4) = *(const float4*)(state + base + (c + 32) * 4);
  }
}

// ---------------------------------------------------------------- k_w_onehot
__global__ __launch_bounds__(256)
void k_w_onehot(const float* __restrict__ Wk, const float* __restrict__ uT,
                const float* __restrict__ vT, float* __restrict__ wu2,
                float* __restrict__ wv, float* __restrict__ out1) {
  const int blk = blockIdx.x;
  const int t = threadIdx.x;
  if (blk < 512) {
    const int e = blk & 255;
    const int part = blk >> 8;     // 0 -> wu2, 1 -> wv
    __shared__ float wrow[256];
    wrow[t] = Wk[e * 256 + t];
    __syncthreads();
    if (part == 0) {
      // thread t = j; lane-coalesced uT reads
#pragma unroll
      for (int h = 0; h < 8; ++h) {
        float acc = 0.0f;
#pragma unroll
        for (int d = 0; d < 32; ++d)
          acc += uT[(h * 32 + d) * 256 + t] * wrow[h * 32 + d];
        wu2[(h * 256 + e) * 256 + t] = acc;
      }
    } else if (t < 32) {
      // thread t = b; lane-coalesced vT reads (32 lanes x 4B)
#pragma unroll
      for (int h = 0; h < 8; ++h) {
        float acc = 0.0f;
#pragma unroll
        for (int d = 0; d < 32; ++d)
          acc += vT[(h * 32 + d) * 32 + t] * wrow[h * 32 + d];
        wv[(t * 8 + h) * 256 + e] = acc;
      }
    }
  } else {
    // role C: out1 one-hot rows q<256 (8 rows per block, 320 float4 per row)
    const int id = blk - 512;      // 0..1023
    const int b = id >> 5, qg = id & 31;
#pragma unroll
    for (int k = 0; k < 8; ++k) {
      const int q = qg * 8 + k;
      float4* row = (float4*)(out1 + ((size_t)(b * 512 + q)) * 1280);
      float4 o = make_float4(0.f, 0.f, 0.f, 0.f);
      if (t == (q >> 2)) {
        const int comp = q & 3;
        if (comp == 0) o.x = 1.f; else if (comp == 1) o.y = 1.f;
        else if (comp == 2) o.z = 1.f; else o.w = 1.f;
      }
      row[t] = o;
      if (t < 64) row[256 + t] = make_float4(0.f, 0.f, 0.f, 0.f);
    }
  }
}

// ---------------------------------------------------------------- k_all
// grid (16 jt, 32 b) = 512 blocks, 512 threads = 8 waves, 2 blocks/CU
// (58.4 KB LDS) -> entire grid co-resident, zero tail.
// Two chunks of 128 e: {stage s_data -> barrier -> compute} x2, acc carried.
// t = jl(0..15)+16*es(0..15)+256*hp(0..1); el = it*16+es (uniform 2-way LDS
// bank aliasing = free). wu2 from global (L2-resident, 32x reuse).
// Reduce: shfl(16,32) -> s_part -> s_tot (LDS) -> 16-lane softmax -> s_a ->
// dependent out0 cols (raw re-read, L2-hot) + out1 sparse rows.
__global__ __launch_bounds__(512)
void k_all(const float* __restrict__ state, const float* __restrict__ o0,
           const float* __restrict__ o1, const float* __restrict__ o2,
           const float* __restrict__ wu2, const float* __restrict__ wv,
           float* __restrict__ out0, float* __restrict__ out1) {
  const int t = threadIdx.x;
  const int jt = blockIdx.x;       // 0..15
  const int b  = blockIdx.y;       // 0..31

  __shared__ float s_data[4][128][17];  // 34.8 KB (reused per chunk)
  __shared__ float s_wvb[2048];         //  8.0 KB  wv[b][h][e], all 256 e
  __shared__ float s_part[8][16][25];   // 12.8 KB
  __shared__ float s_tot[44][16];       //  2.8 KB
  __shared__ float s_a[16][4];

  for (int i = t; i < 2048; i += 512) s_wvb[i] = wv[b * 2048 + i];

  const int jl = t & 15;
  const int es = (t >> 4) & 15;    // 0..15
  const int hp = t >> 8;           // 0..1
  const int j = jt * 16 + jl;

  // acc[hh*5+c]: c=0..3 dR(state,o0,o1,o2), c=4 dO(ones); 20..23 raw sums
  float acc[24];
#pragma unroll
  for (int k = 0; k < 24; ++k) acc[k] = 0.f;

  const float* pwu = wu2 + (size_t)hp * 4 * 256 * 256 + j;  // + (hh*256+e)*256
  const float* pwvb = s_wvb + hp * 4 * 256;                 // + hh*256+e

#pragma unroll
  for (int chunk = 0; chunk < 2; ++chunk) {
    // ---- stage data tile for this chunk: 2048 float4 cells, 4 per thread
    __syncthreads();               // protect s_data reuse (chunk 1)
#pragma unroll
    for (int rep = 0; rep < 4; ++rep) {
      const int c = t + rep * 512;   // 0..2047
      const int m = c >> 9;          // 0..3
      const int r = c & 511;
      const int e = r >> 2;          // 0..127
      const int jq = r & 3;          // 0..3
      const int ge = chunk * 128 + e;
      const int j0 = jt * 16 + jq * 4;
      const float* src;
      if (m == 0)      src = state + ((size_t)(b * 256 + ge)) * 512 + 256 + j0;
      else if (m == 1) src = o0 + ((size_t)(b * 256 + ge)) * 256 + j0;
      else if (m == 2) src = o1 + ((size_t)(b * 256 + ge)) * 256 + j0;
      else             src = o2 + ((size_t)(b * 256 + ge)) * 256 + j0;
      const float4 v4 = *(const float4*)src;
      const int jb = jq * 4;
      s_data[m][e][jb]   = v4.x; s_data[m][e][jb+1] = v4.y;
      s_data[m][e][jb+2] = v4.z; s_data[m][e][jb+3] = v4.w;
    }
    __syncthreads();

#pragma unroll
    for (int it = 0; it < 8; ++it) {
      const int el = it * 16 + es;   // 0..127 within chunk
      const int e = chunk * 128 + el;
      const float s  = s_data[0][el][jl];
      const float x0 = s_data[1][el][jl];
      const float x1 = s_data[2][el][jl];
      const float x2 = s_data[3][el][jl];
      acc[20] += s; acc[21] += x0; acc[22] += x1; acc[23] += x2;
#pragma unroll
      for (int hh = 0; hh < 4; ++hh) {
        const float w = pwu[(size_t)(hh * 256 + e) * 256] + pwvb[hh * 256 + e];
        acc[hh * 5 + 0] += s * w;  acc[hh * 5 + 1] += x0 * w;
        acc[hh * 5 + 2] += x1 * w; acc[hh * 5 + 3] += x2 * w;
        acc[hh * 5 + 4] += w;
      }
    }
  }

  // reduce over es low bits (lane bits 4,5)
#pragma unroll
  for (int k = 0; k < 24; ++k) {
    acc[k] += __shfl_xor(acc[k], 16);
    acc[k] += __shfl_xor(acc[k], 32);
  }
  if ((t & 48) == 0) {
    const int w = t >> 6;          // 0..7
    float* p = &s_part[w][jl][0];
#pragma unroll
    for (int k = 0; k < 24; ++k) p[k] = acc[k];
  }
  __syncthreads();

  // combine waves into s_tot: k = h*5+c (0..39), raw sums at 40..43
  if (t < 16) {
#pragma unroll
    for (int k = 0; k < 20; ++k)
      s_tot[k][t] = s_part[0][t][k] + s_part[1][t][k] + s_part[2][t][k] + s_part[3][t][k];
#pragma unroll
    for (int c = 0; c < 4; ++c)
      s_tot[40 + c][t] = s_part[0][t][20 + c] + s_part[1][t][20 + c] +
                         s_part[2][t][20 + c] + s_part[3][t][20 + c];
  } else if (t >= 256 && t < 272) {
    const int l = t & 15;
#pragma unroll
    for (int k = 0; k < 20; ++k)
      s_tot[20 + k][l] = s_part[4][l][k] + s_part[5][l][k] + s_part[6][l][k] + s_part[7][l][k];
  }
  __syncthreads();

  if (t < 16) {
    float tot[44];
#pragma unroll
    for (int k = 0; k < 44; ++k) tot[k] = s_tot[k][t];
    const float m0 = tot[40] * (1.f / 256.f), m1 = tot[41] * (1.f / 256.f);
    const float m2 = tot[42] * (1.f / 256.f), m3 = tot[43] * (1.f / 256.f);
    const float inv = 0.17677669529663687f;  // 1/sqrt(32)
    float am0 = 0.f, am1 = 0.f, am2 = 0.f, am3 = 0.f;
#pragma unroll
    for (int h = 0; h < 8; ++h) {
      const float dO = tot[h * 5 + 4];
      const float s0 = (tot[h * 5 + 0] - m0 * dO) * inv;
      const float s1 = (tot[h * 5 + 1] - m1 * dO) * inv;
      const float s2 = (tot[h * 5 + 2] - m2 * dO) * inv;
      const float s3 = (tot[h * 5 + 3] - m3 * dO) * inv;
      const float mx = fmaxf(fmaxf(s0, s1), fmaxf(s2, s3));
      const float e0 = expf(s0 - mx), e1 = expf(s1 - mx);
      const float e2 = expf(s2 - mx), e3 = expf(s3 - mx);
      const float r = 1.f / (e0 + e1 + e2 + e3);
      am0 += e0 * r; am1 += e1 * r; am2 += e2 * r; am3 += e3 * r;
    }
    s_a[t][0] = am0 * 0.125f; s_a[t][1] = am1 * 0.125f;
    s_a[t][2] = am2 * 0.125f; s_a[t][3] = am3 * 0.125f;
  }
  __syncthreads();

  // ---- out0[b][e][256+j] (raw inputs L2-hot: this block just read them)
  {
    const int jl2 = t & 15;
    const int er = t >> 4;         // 0..31
    const float a0 = s_a[jl2][0], a1 = s_a[jl2][1];
    const float a2 = s_a[jl2][2], a3 = s_a[jl2][3];
    const int jj = jt * 16 + jl2;
#pragma unroll
    for (int k = 0; k < 8; ++k) {
      const int e = er + 32 * k;
      const size_t idxS = ((size_t)(b * 256 + e)) * 512 + 256 + jj;
      const size_t idxO = ((size_t)(b * 256 + e)) * 256 + jj;
      out0[idxS] = a0 * state[idxS] + a1 * o0[idxO] + a2 * o1[idxO] + a3 * o2[idxO];
    }
  }

  // ---- out1 rows q = 256+j (4 sparse values, rest zero)
  {
    const int r = t >> 5;          // 0..15 (row within tile)
    const int c = t & 31;
    const int j3 = jt * 16 + r;
    const int q = 256 + j3;
    const int comp = j3 & 3;
    const int tc0 = (256 + j3) >> 2, tc1 = (512 + j3) >> 2;
    const int tc2 = (768 + j3) >> 2, tc3 = (1024 + j3) >> 2;
    const float av0 = s_a[r][0], av1 = s_a[r][1];
    const float av2 = s_a[r][2], av3 = s_a[r][3];
    float4* orow = (float4*)(out1 + ((size_t)(b * 512 + q)) * 1280);
#pragma unroll
    for (int k = 0; k < 10; ++k) {
      const int c4 = c + 32 * k;
      float4 o = make_float4(0.f, 0.f, 0.f, 0.f);
      float val = 0.f; bool hit = false;
      if (c4 == tc0)      { val = av0; hit = true; }
      else if (c4 == tc1) { val = av1; hit = true; }
      else if (c4 == tc2) { val = av2; hit = true; }
      else if (c4 == tc3) { val = av3; hit = true; }
      if (hit) {
        if (comp == 0) o.x = val; else if (comp == 1) o.y = val;
        else if (comp == 2) o.z = val; else o.w = val;
      }
      orow[c4] = o;
    }
  }
}

extern "C" void kernel_launch(void* const* d_in, const int* in_sizes, int n_in,
                              void* d_out, int out_size, void* d_ws, size_t ws_size,
                              hipStream_t stream) {
  const float* state = (const float*)d_in[0];
  const float* obs0  = (const float*)d_in[1];
  const float* obs1  = (const float*)d_in[2];
  const float* obs2  = (const float*)d_in[3];
  const float* Q     = (const float*)d_in[4];
  const float* Wq    = (const float*)d_in[5];
  const float* bq    = (const float*)d_in[6];
  const float* Wk    = (const float*)d_in[7];
  // d_in[8] = bk: cancels in the 4-way softmax (shift invariance), unused.

  float* out0 = (float*)d_out;                       // new_state [32,256,512]
  float* out1 = out0 + (size_t)32 * 256 * 512;       // atten [32,512,1280]

  float* ws  = (float*)d_ws;
  float* uT  = ws;              // 65536  [256f][256j]
  float* vT  = uT + 65536;      // 8192   [256f][32b]
  float* wu2 = vT + 8192;       // 524288
  float* wv  = wu2 + 524288;    // 65536

  k_uv_copy<<<1312, 256, 0, stream>>>(Q, Wq, bq, state, uT, vT, out0);
  k_w_onehot<<<1536, 256, 0, stream>>>(Wk, uT, vT, wu2, wv, out1);
  k_all<<<dim3(16, 32), 512, 0, stream>>>(state, obs0, obs1, obs2, wu2, wv, out0, out1);
}